// Round 3
// baseline (228.520 us; speedup 1.0000x reference)
//
#include <hip/hip_runtime.h>
#include <hip/hip_bf16.h>
#include <math.h>
#include <stdint.h>

// Disable FP contraction: tie-breaking (quality = 1e8 - area, ulp=8 at 1e8)
// and decode must bit-match the mul-then-round numpy reference.
#pragma clang fp contract(off)

#define NB   16
#define NC   20
#define NM   64
#define NT   21504
#define OFF1 16384
#define OFF2 20480
#define TOPK 1000
#define DELTA_OFF 80000L
#define CTR_OFF   1456256L

// workspace layout (float units). matrix aliases scores/boxesw (dead after k_select).
#define WS_SCORES   0L
#define WS_BOXESW   344064L
#define WS_CIDW     1720320L
#define WS_TOPSC    2064384L
#define WS_TOPBOX   2080768L
#define WS_TOPSHIFT 2146304L
#define WS_TOPAREA  2211840L
#define WS_ACT      2228224L   // 256 x u64
#define WS_MATRIX   0L         // 16*1024*16 u64 = 2 MB, aliases scores+boxesw head

// ---------- dtype helpers (bf: 0 = float32, 1 = bf16) ----------
__device__ __forceinline__ int detect_bf(const void* locs0) {
  unsigned w = *(const unsigned*)locs0;      // f32 4.0 = 0x40800000 (low16==0)
  return ((w & 0xFFFFu) == 0u) ? 0 : 1;
}
__device__ __forceinline__ float ldin(const void* p, long i, int bf) {
  if (bf) return __uint_as_float(((unsigned)((const unsigned short*)p)[i]) << 16);
  return ((const float*)p)[i];
}
__device__ __forceinline__ unsigned short f2bf(float v) {
  unsigned w = __float_as_uint(v);
  return (unsigned short)((w + 0x7FFFu + ((w >> 16) & 1u)) >> 16);  // RNE
}
__device__ __forceinline__ void stout(void* p, long i, float v, int bf) {
  if (bf) ((unsigned short*)p)[i] = f2bf(v);
  else    ((float*)p)[i] = v;
}

// ---------- K1: fused targets + scores/decode ----------
__global__ __launch_bounds__(256)
void k_main(const void* locs0, const void* locs1, const void* locs2,
            const void* gt,
            const void* cls0, const void* cls1, const void* cls2,
            const void* reg0, const void* reg1, const void* reg2,
            const void* ctr0, const void* ctr1, const void* ctr2,
            void* out, float* scores, float* boxesw, float* cidw) {
  __shared__ float sgt[NM * 5];
  __shared__ float scls[256 * 21];   // 256 locations x 20 classes, pad stride 21
  const int bf  = detect_bf(locs0);
  const int b   = blockIdx.y;
  const int blk = blockIdx.x;
  const int tid = threadIdx.x;
  const int n   = blk * 256 + tid;

  const void *L, *CL, *RG, *CT; int NL, base; float stride, lower, upper;
  if (blk < 64)      { L=locs0; CL=cls0; RG=reg0; CT=ctr0; NL=16384; base=0;    stride=8.f;  lower=0.f;   upper=64.f; }
  else if (blk < 80) { L=locs1; CL=cls1; RG=reg1; CT=ctr1; NL=4096;  base=OFF1; stride=16.f; lower=64.f;  upper=128.f; }
  else               { L=locs2; CL=cls2; RG=reg2; CT=ctr2; NL=1024;  base=OFF2; stride=32.f; lower=128.f; upper=INFINITY; }
  const int nl     = n - base;
  const int nlBase = blk * 256 - base;

  for (int i = tid; i < NM * 5; i += 256) sgt[i] = ldin(gt, (long)b * NM * 5 + i, bf);

  long cbase = ((long)b * NL + nlBase) * NC;   // divisible by 4 (NC=20)
  if (!bf) {
    const float4* p = (const float4*)((const float*)CL + cbase);
    for (int i = tid; i < 1280; i += 256) {
      float4 v = p[i];
      int e = i * 4;
      scls[( e      / 20) * 21 +  e      % 20] = v.x;
      scls[((e + 1) / 20) * 21 + (e + 1) % 20] = v.y;
      scls[((e + 2) / 20) * 21 + (e + 2) % 20] = v.z;
      scls[((e + 3) / 20) * 21 + (e + 3) % 20] = v.w;
    }
  } else {
    const unsigned* p = (const unsigned*)((const unsigned short*)CL + cbase);
    for (int i = tid; i < 2560; i += 256) {
      unsigned w = p[i];
      int e = i * 2;
      scls[( e      / 20) * 21 +  e      % 20] = __uint_as_float((w & 0xFFFFu) << 16);
      scls[((e + 1) / 20) * 21 + (e + 1) % 20] = __uint_as_float(w & 0xFFFF0000u);
    }
  }
  __syncthreads();

  float cx = ldin(L, (long)nl * 2 + 0, bf);
  float cy = ldin(L, (long)nl * 2 + 1, bf);

  // ---- GT matching / targets ----
  float best = -1.0f; int bi = 0;              // argmax-first (strict >)
  for (int m = 0; m < NM; ++m) {
    float g0 = sgt[m*5+0], g1 = sgt[m*5+1], g2 = sgt[m*5+2], g3 = sgt[m*5+3];
    float l = cx - g0, t = cy - g1, r = g2 - cx, d = g3 - cy;
    float mn = fminf(fminf(l, t), fminf(r, d));
    float mx = fmaxf(fmaxf(l, t), fmaxf(r, d));
    bool  ok = (mn > 0.f) && (mx > lower) && (mx < upper);
    float area = (g2 - g0) * (g3 - g1);
    float q = ok ? (100000000.0f - area) : 0.f;
    if (q > best) { best = q; bi = m; }
  }
  float d0, d1, d2, d3, ctrv;
  if (best < 1e-5f) {
    d0 = d1 = d2 = d3 = -1.f; ctrv = -1.f;
  } else {
    float m0 = sgt[bi*5+0], m1 = sgt[bi*5+1], m2 = sgt[bi*5+2], m3 = sgt[bi*5+3];
    d0 = (cx - m0) / stride; d1 = (cy - m1) / stride;
    d2 = (m2 - cx) / stride; d3 = (m3 - cy) / stride;
    float mnlr = fminf(d0, d2), mntb = fminf(d1, d3);
    float mxlr = fmaxf(d0, d2), mxtb = fmaxf(d1, d3);
    ctrv = sqrtf((mnlr * mntb) / (mxlr * mxtb));
  }
  long dbase = DELTA_OFF + ((long)b * NT + n) * 4;
  if (!bf) {
    *(float4*)((float*)out + dbase) = make_float4(d0, d1, d2, d3);
  } else {
    ushort4 v; v.x = f2bf(d0); v.y = f2bf(d1); v.z = f2bf(d2); v.w = f2bf(d3);
    *(ushort4*)((unsigned short*)out + dbase) = v;
  }
  stout(out, CTR_OFF + (long)b * NT + n, ctrv, bf);

  // ---- scores + decode ----
  float ct  = ldin(CT, (long)b * NL + nl, bf);
  float sct = 1.0f / (1.0f + expf(-ct));
  float smax = -1.0f; int ci = 0;              // argmax over sqrt-scores, strict >
  for (int c = 0; c < NC; ++c) {
    float v  = scls[tid * 21 + c];
    float sv = 1.0f / (1.0f + expf(-v));
    float s  = sqrtf(sv * sct);
    if (s > smax) { smax = s; ci = c; }
  }
  float r0, r1, r2, r3;
  long rbase = ((long)b * NL + nl) * 4;
  if (!bf) {
    float4 rv = *(const float4*)((const float*)RG + rbase);
    r0 = rv.x; r1 = rv.y; r2 = rv.z; r3 = rv.w;
  } else {
    uint2 rw = *(const uint2*)((const unsigned short*)RG + rbase);
    r0 = __uint_as_float((rw.x & 0xFFFFu) << 16); r1 = __uint_as_float(rw.x & 0xFFFF0000u);
    r2 = __uint_as_float((rw.y & 0xFFFFu) << 16); r3 = __uint_as_float(rw.y & 0xFFFF0000u);
  }
  r0 = fmaxf(r0, 0.f); r1 = fmaxf(r1, 0.f); r2 = fmaxf(r2, 0.f); r3 = fmaxf(r3, 0.f);
  long o = (long)b * NT + n;
  scores[o] = smax;
  *(float4*)(boxesw + o * 4) =
      make_float4(cx - r0 * stride, cy - r1 * stride, cx + r2 * stride, cy + r3 * stride);
  cidw[o] = (float)ci;
}

// ---------- K2: exact top-1000 select + sort; emit sorted top arrays ----------
__global__ __launch_bounds__(1024)
void k_select(const float* scores, const float* boxesw, const float* cidw,
              float* topScore, float* topBox, float* topShift, float* topArea,
              unsigned long long* actInit) {
  const int b    = blockIdx.x;
  const int tid  = threadIdx.x;
  const int wid  = tid >> 6;
  const int lane = tid & 63;
  const float* sb = scores + (long)b * NT;

  __shared__ unsigned long long selKeys[1024];
  __shared__ unsigned wcnt[16][3];
  __shared__ unsigned selCnt;
  __shared__ float redf[16];
  __shared__ float sMaxC;

  // my 21 inverted keys (coalesced, once)
  unsigned inv[21];
#pragma unroll
  for (int k = 0; k < 21; ++k)
    inv[k] = ~__float_as_uint(sb[tid + k * 1024]);

  // --- 2-bit-per-round binary search for V = 1000th smallest inv ---
  // scores in (0,1] -> inv in [0xC07FFFFF, 0xFFFFFFFF]: top 2 bits always 11.
  unsigned V = 0xC0000000u;
  for (int s = 28; s >= 0; s -= 2) {
    unsigned T1 = V | (1u << s), T2 = V | (2u << s), T3 = V | (3u << s);
    unsigned c1 = 0, c2 = 0, c3 = 0;
#pragma unroll
    for (int k = 0; k < 21; ++k) {
      c1 += (unsigned)__popcll(__ballot(inv[k] < T1));
      c2 += (unsigned)__popcll(__ballot(inv[k] < T2));
      c3 += (unsigned)__popcll(__ballot(inv[k] < T3));
    }
    if (lane == 0) { wcnt[wid][0] = c1; wcnt[wid][1] = c2; wcnt[wid][2] = c3; }
    __syncthreads();
    unsigned t1 = 0, t2 = 0, t3 = 0;
    for (int w = 0; w < 16; ++w) { t1 += wcnt[w][0]; t2 += wcnt[w][1]; t3 += wcnt[w][2]; }
    unsigned p = (t3 < TOPK) ? 3u : (t2 < TOPK) ? 2u : (t1 < TOPK) ? 1u : 0u;
    V |= p << s;
    __syncthreads();
  }

  // --- gather: inv < V first (<=999), then ties at V ---
  if (tid == 0) selCnt = 0u;
  __syncthreads();
#pragma unroll
  for (int k = 0; k < 21; ++k)
    if (inv[k] < V) {
      unsigned p = atomicAdd(&selCnt, 1u);
      if (p < 1024u) selKeys[p] = ((unsigned long long)inv[k] << 32) | (unsigned)(tid + k * 1024);
    }
  __syncthreads();
#pragma unroll
  for (int k = 0; k < 21; ++k)
    if (inv[k] == V) {
      unsigned p = atomicAdd(&selCnt, 1u);
      if (p < 1024u) selKeys[p] = ((unsigned long long)inv[k] << 32) | (unsigned)(tid + k * 1024);
    }
  __syncthreads();
  unsigned total = selCnt < 1024u ? selCnt : 1024u;
  if ((unsigned)tid >= total) selKeys[tid] = 0xFFFFFFFFFFFFFFFFull;
  __syncthreads();

  // --- bitonic sort ascending: (inv asc, idx asc) == (score desc, idx asc) ---
  for (unsigned k = 2; k <= 1024; k <<= 1) {
    for (unsigned j = k >> 1; j > 0; j >>= 1) {
      unsigned ixj = (unsigned)tid ^ j;
      if (ixj > (unsigned)tid) {
        unsigned long long a = selKeys[tid], c = selKeys[ixj];
        bool up = ((tid & k) == 0);
        if (up ? (a > c) : (a < c)) { selKeys[tid] = c; selKeys[ixj] = a; }
      }
      __syncthreads();
    }
  }

  // --- epilogue: gather boxes, max_coord, shift, write top arrays ---
  unsigned long long key = selKeys[tid];
  float sc = __uint_as_float(~(unsigned)(key >> 32));
  float4 bv = make_float4(0.f, 0.f, 0.f, 0.f);
  float cid = 0.f;
  if (tid < TOPK) {
    long o = (long)b * NT + (unsigned)key;
    bv = *(const float4*)(boxesw + o * 4);
    cid = cidw[o];
  } else sc = 0.f;

  float loc = (tid < TOPK)
      ? ((sc > 0.3f) ? fmaxf(fmaxf(bv.x, bv.y), fmaxf(bv.z, bv.w)) : 0.0f)
      : -INFINITY;
  for (int o = 32; o > 0; o >>= 1) loc = fmaxf(loc, __shfl_down(loc, o));
  if (lane == 0) redf[wid] = loc;
  __syncthreads();
  if (tid == 0) {
    float m = redf[0];
    for (int w = 1; w < 16; ++w) m = fmaxf(m, redf[w]);
    sMaxC = m;
  }
  __syncthreads();

  float offm = sMaxC + 1.0f;
  long tb = (long)b * 1024 + tid;
  if (tid < TOPK) {
    float o4 = cid * offm;
    float s0 = bv.x + o4, s1 = bv.y + o4, s2 = bv.z + o4, s3 = bv.w + o4;
    *(float4*)(topShift + tb * 4) = make_float4(s0, s1, s2, s3);
    topArea[tb]  = (s2 - s0) * (s3 - s1);
    *(float4*)(topBox + tb * 4) = bv;
    topScore[tb] = sc;
  } else {
    *(float4*)(topShift + tb * 4) = make_float4(0.f, 0.f, 0.f, 0.f);
    topArea[tb]  = 0.f;
    *(float4*)(topBox + tb * 4) = make_float4(0.f, 0.f, 0.f, 0.f);
    topScore[tb] = 0.f;
  }
  unsigned long long vb = __ballot((tid < TOPK) && (sc > 0.3f));
  if (lane == 0) actInit[b * 16 + wid] = vb;
}

// ---------- K3: suppression bit-matrix (massively parallel IoU) ----------
// block (wh, b): w = wh>>1 (u64 word), h = wh&1 (u32 half). thread i = row.
// matrix[(b*1024+i)*32 + wh] (u32) = bits j = w*64+h*32+k, k=0..31.
__global__ __launch_bounds__(1024)
void k_iou(const float* topShift, const float* topArea, unsigned* matrix) {
  const int wh  = blockIdx.x;
  const int b   = blockIdx.y;
  const int tid = threadIdx.x;
  const int jbase = (wh >> 1) * 64 + (wh & 1) * 32;
  __shared__ float jx0[32], jy0[32], jx1[32], jy1[32], ja[32];
  if (tid < 32) {
    long tj = (long)b * 1024 + jbase + tid;
    float4 s = *(const float4*)(topShift + tj * 4);
    jx0[tid] = s.x; jy0[tid] = s.y; jx1[tid] = s.z; jy1[tid] = s.w;
    ja[tid] = topArea[tj];
  }
  __syncthreads();
  long ti = (long)b * 1024 + tid;
  float4 si = *(const float4*)(topShift + ti * 4);
  float ai  = topArea[ti];
  unsigned word = 0u;
  for (int k = 0; k < 32; ++k) {
    float xx1 = fmaxf(si.x, jx0[k]);
    float yy1 = fmaxf(si.y, jy0[k]);
    float xx2 = fminf(si.z, jx1[k]);
    float yy2 = fminf(si.w, jy1[k]);
    float inter = fmaxf(xx2 - xx1, 0.f) * fmaxf(yy2 - yy1, 0.f);
    float iou = inter / (ai + ja[k] - inter);   // exact div: matches ref rounding
    if (!(iou <= 0.5f)) word |= (1u << k);      // NaN suppresses, like the ref
  }
  matrix[ti * 32 + wh] = word;
}

// ---------- K4: greedy scan over bit-matrix + det write ----------
__global__ __launch_bounds__(256)
void k_scan(const unsigned long long* matrix, const unsigned long long* actInit,
            const float* topBox, const float* topScore, void* out, const void* locs0) {
  const int bf   = detect_bf(locs0);
  const int b    = blockIdx.x;
  const int tid  = threadIdx.x;
  const int wid  = tid >> 6;
  const int lane = tid & 63;
  const unsigned long long* M = matrix + (long)b * 1024 * 16;

  __shared__ unsigned long long rows[2][64][16];   // double-buffered 64-row chunks
  __shared__ unsigned long long keepSh[16];

  unsigned long long act = 0ull, keep = 0ull;
  if (wid == 0 && lane < 16) act = actInit[b * 16 + lane];

  // preload chunk 0
  for (int t = tid; t < 1024; t += 256)
    rows[0][t >> 4][t & 15] = M[t];
  __syncthreads();

  int kept = 0;
  for (int c = 0; c < 16; ++c) {
    if (wid > 0) {
      if (c < 15) {
        for (int t = tid - 64; t < 1024; t += 192)
          rows[(c + 1) & 1][t >> 4][t & 15] = M[(long)(c + 1) * 1024 + t];
      }
    } else {
      unsigned long long cur = __shfl(act, c);   // lane c's word, broadcast
      while (cur && kept < 100) {
        int k = __ffsll((unsigned long long)cur) - 1;
        ++kept;
        if (lane == c) keep |= (1ull << k);
        unsigned long long r = (lane < 16) ? rows[c & 1][k][lane] : 0ull;
        act &= ~r;                               // row's self-bit clears bit i too
        cur = __shfl(act, c);
      }
    }
    __syncthreads();
  }
  if (wid == 0 && lane < 16) keepSh[lane] = keep;
  __syncthreads();

  for (int r = tid; r < TOPK; r += 256) {
    bool kp = (keepSh[r >> 6] >> (r & 63)) & 1ull;
    long tb = (long)b * 1024 + r;
    float4 bx = *(const float4*)(topBox + tb * 4);
    float sc  = topScore[tb];
    long o = ((long)b * TOPK + r) * 5;
    stout(out, o + 0, kp ? bx.x : 0.f, bf);
    stout(out, o + 1, kp ? bx.y : 0.f, bf);
    stout(out, o + 2, kp ? bx.z : 0.f, bf);
    stout(out, o + 3, kp ? bx.w : 0.f, bf);
    stout(out, o + 4, kp ? sc   : 0.f, bf);
  }
}

extern "C" void kernel_launch(void* const* d_in, const int* in_sizes, int n_in,
                              void* d_out, int out_size, void* d_ws, size_t ws_size,
                              hipStream_t stream) {
  const void* locs0 = d_in[0];
  const void* locs1 = d_in[1];
  const void* locs2 = d_in[2];
  const void* gt    = d_in[3];

  int ic[3], ir[3], it[3];
  if (n_in >= 13 && in_sizes[5] == 16 * 4096 * 20) {
    ic[0]=4; ic[1]=5; ic[2]=6;  ir[0]=7; ir[1]=8; ir[2]=9;  it[0]=10; it[1]=11; it[2]=12;
  } else {
    ic[0]=4; ic[1]=7; ic[2]=10; ir[0]=5; ir[1]=8; ir[2]=11; it[0]=6;  it[1]=9;  it[2]=12;
  }
  const void* cls0 = d_in[ic[0]]; const void* cls1 = d_in[ic[1]]; const void* cls2 = d_in[ic[2]];
  const void* reg0 = d_in[ir[0]]; const void* reg1 = d_in[ir[1]]; const void* reg2 = d_in[ir[2]];
  const void* ctr0 = d_in[it[0]]; const void* ctr1 = d_in[it[1]]; const void* ctr2 = d_in[it[2]];

  float* ws       = (float*)d_ws;
  float* scores   = ws + WS_SCORES;
  float* boxesw   = ws + WS_BOXESW;
  float* cidw     = ws + WS_CIDW;
  float* topScore = ws + WS_TOPSC;
  float* topBox   = ws + WS_TOPBOX;
  float* topShift = ws + WS_TOPSHIFT;
  float* topArea  = ws + WS_TOPAREA;
  unsigned long long* actInit = (unsigned long long*)(ws + WS_ACT);
  unsigned*           matrix32 = (unsigned*)(ws + WS_MATRIX);
  unsigned long long* matrix64 = (unsigned long long*)(ws + WS_MATRIX);

  k_main<<<dim3(NT / 256, NB), 256, 0, stream>>>(locs0, locs1, locs2, gt,
                                                 cls0, cls1, cls2,
                                                 reg0, reg1, reg2,
                                                 ctr0, ctr1, ctr2,
                                                 d_out, scores, boxesw, cidw);
  k_select<<<NB, 1024, 0, stream>>>(scores, boxesw, cidw,
                                    topScore, topBox, topShift, topArea, actInit);
  k_iou<<<dim3(32, NB), 1024, 0, stream>>>(topShift, topArea, matrix32);
  k_scan<<<NB, 256, 0, stream>>>(matrix64, actInit, topBox, topScore, d_out, locs0);
}

// Round 4
// 186.271 us; speedup vs baseline: 1.2268x; 1.2268x over previous
//
#include <hip/hip_runtime.h>
#include <hip/hip_bf16.h>
#include <math.h>
#include <stdint.h>

// Disable FP contraction: tie-breaking (quality = 1e8 - area, ulp=8 at 1e8)
// and decode must bit-match the mul-then-round numpy reference.
#pragma clang fp contract(off)

#define NB   16
#define NC   20
#define NM   64
#define NT   21504
#define OFF1 16384
#define OFF2 20480
#define TOPK 1000
#define DELTA_OFF 80000L
#define CTR_OFF   1456256L

// workspace layout (float units). matrix aliases scores/boxesw (dead after k_select).
#define WS_SCORES   0L
#define WS_BOXESW   344064L
#define WS_CIDW     1720320L
#define WS_TOPSC    2064384L
#define WS_TOPBOX   2080768L
#define WS_TOPSHIFT 2146304L
#define WS_TOPAREA  2211840L
#define WS_ACT      2228224L   // 256 x u64
#define WS_MATRIX   0L         // 16*1024*16 u64 = 2 MB, aliases scores+boxesw head

// ---------- dtype helpers (bf: 0 = float32, 1 = bf16) ----------
__device__ __forceinline__ int detect_bf(const void* locs0) {
  unsigned w = *(const unsigned*)locs0;      // f32 4.0 = 0x40800000 (low16==0)
  return ((w & 0xFFFFu) == 0u) ? 0 : 1;
}
__device__ __forceinline__ float ldin(const void* p, long i, int bf) {
  if (bf) return __uint_as_float(((unsigned)((const unsigned short*)p)[i]) << 16);
  return ((const float*)p)[i];
}
__device__ __forceinline__ unsigned short f2bf(float v) {
  unsigned w = __float_as_uint(v);
  return (unsigned short)((w + 0x7FFFu + ((w >> 16) & 1u)) >> 16);  // RNE
}
__device__ __forceinline__ void stout(void* p, long i, float v, int bf) {
  if (bf) ((unsigned short*)p)[i] = f2bf(v);
  else    ((float*)p)[i] = v;
}

// ---------- K1: fused targets + scores/decode ----------
__global__ __launch_bounds__(256)
void k_main(const void* locs0, const void* locs1, const void* locs2,
            const void* gt,
            const void* cls0, const void* cls1, const void* cls2,
            const void* reg0, const void* reg1, const void* reg2,
            const void* ctr0, const void* ctr1, const void* ctr2,
            void* out, float* scores, float* boxesw, float* cidw) {
  __shared__ float sgt[NM * 5];
  const int bf  = detect_bf(locs0);
  const int b   = blockIdx.y;
  const int blk = blockIdx.x;
  const int tid = threadIdx.x;
  const int n   = blk * 256 + tid;

  const void *L, *CL, *RG, *CT; int NL, base; float stride, lower, upper;
  if (blk < 64)      { L=locs0; CL=cls0; RG=reg0; CT=ctr0; NL=16384; base=0;    stride=8.f;  lower=0.f;   upper=64.f; }
  else if (blk < 80) { L=locs1; CL=cls1; RG=reg1; CT=ctr1; NL=4096;  base=OFF1; stride=16.f; lower=64.f;  upper=128.f; }
  else               { L=locs2; CL=cls2; RG=reg2; CT=ctr2; NL=1024;  base=OFF2; stride=32.f; lower=128.f; upper=INFINITY; }
  const int nl = n - base;

  for (int i = tid; i < NM * 5; i += 256) sgt[i] = ldin(gt, (long)b * NM * 5 + i, bf);
  __syncthreads();

  float cx = ldin(L, (long)nl * 2 + 0, bf);
  float cy = ldin(L, (long)nl * 2 + 1, bf);

  // ---- GT matching / targets ----
  float best = -1.0f; int bi = 0;              // argmax-first (strict >)
  for (int m = 0; m < NM; ++m) {
    float g0 = sgt[m*5+0], g1 = sgt[m*5+1], g2 = sgt[m*5+2], g3 = sgt[m*5+3];
    float l = cx - g0, t = cy - g1, r = g2 - cx, d = g3 - cy;
    float mn = fminf(fminf(l, t), fminf(r, d));
    float mx = fmaxf(fmaxf(l, t), fmaxf(r, d));
    bool  ok = (mn > 0.f) && (mx > lower) && (mx < upper);
    float area = (g2 - g0) * (g3 - g1);
    float q = ok ? (100000000.0f - area) : 0.f;
    if (q > best) { best = q; bi = m; }
  }
  float d0, d1, d2, d3, ctrv;
  if (best < 1e-5f) {
    d0 = d1 = d2 = d3 = -1.f; ctrv = -1.f;
  } else {
    float m0 = sgt[bi*5+0], m1 = sgt[bi*5+1], m2 = sgt[bi*5+2], m3 = sgt[bi*5+3];
    d0 = (cx - m0) / stride; d1 = (cy - m1) / stride;
    d2 = (m2 - cx) / stride; d3 = (m3 - cy) / stride;
    float mnlr = fminf(d0, d2), mntb = fminf(d1, d3);
    float mxlr = fmaxf(d0, d2), mxtb = fmaxf(d1, d3);
    ctrv = sqrtf((mnlr * mntb) / (mxlr * mxtb));
  }
  long dbase = DELTA_OFF + ((long)b * NT + n) * 4;
  if (!bf) {
    *(float4*)((float*)out + dbase) = make_float4(d0, d1, d2, d3);
  } else {
    ushort4 v; v.x = f2bf(d0); v.y = f2bf(d1); v.z = f2bf(d2); v.w = f2bf(d3);
    *(ushort4*)((unsigned short*)out + dbase) = v;
  }
  stout(out, CTR_OFF + (long)b * NT + n, ctrv, bf);

  // ---- scores: argmax over sigmoid == argmax over logits (monotone) ----
  float ct  = ldin(CT, (long)b * NL + nl, bf);
  float sct = 1.0f / (1.0f + expf(-ct));

  float cl[NC];
  long cb = ((long)b * NL + nl) * NC;
  if (!bf) {
    const float4* p = (const float4*)((const float*)CL + cb);   // cb*4 % 16 == 0
#pragma unroll
    for (int i = 0; i < 5; ++i) {
      float4 q = p[i];
      cl[4*i+0] = q.x; cl[4*i+1] = q.y; cl[4*i+2] = q.z; cl[4*i+3] = q.w;
    }
  } else {
    const uint2* p = (const uint2*)((const unsigned short*)CL + cb);  // cb*2 % 8 == 0
#pragma unroll
    for (int i = 0; i < 5; ++i) {
      uint2 q = p[i];
      cl[4*i+0] = __uint_as_float((q.x & 0xFFFFu) << 16);
      cl[4*i+1] = __uint_as_float(q.x & 0xFFFF0000u);
      cl[4*i+2] = __uint_as_float((q.y & 0xFFFFu) << 16);
      cl[4*i+3] = __uint_as_float(q.y & 0xFFFF0000u);
    }
  }
  float vmax = cl[0], v2 = -INFINITY; int ci = 0;
#pragma unroll
  for (int c = 1; c < NC; ++c) {
    if (cl[c] > vmax) { v2 = vmax; vmax = cl[c]; ci = c; }
    else if (cl[c] > v2) v2 = cl[c];
  }
  float smax;
  if (vmax - v2 < 1e-3f) {
    // sigmoid-plateau risk: replicate the reference loop exactly (strict >, first idx)
    smax = -1.0f; ci = 0;
    for (int c = 0; c < NC; ++c) {
      float sv = 1.0f / (1.0f + expf(-cl[c]));
      float s  = sqrtf(sv * sct);
      if (s > smax) { smax = s; ci = c; }
    }
  } else {
    float sv = 1.0f / (1.0f + expf(-vmax));
    smax = sqrtf(sv * sct);      // == ref's max: RN is monotone under *sct and sqrt
  }

  // ---- decode ----
  float r0, r1, r2, r3;
  long rbase = ((long)b * NL + nl) * 4;
  if (!bf) {
    float4 rv = *(const float4*)((const float*)RG + rbase);
    r0 = rv.x; r1 = rv.y; r2 = rv.z; r3 = rv.w;
  } else {
    uint2 rw = *(const uint2*)((const unsigned short*)RG + rbase);
    r0 = __uint_as_float((rw.x & 0xFFFFu) << 16); r1 = __uint_as_float(rw.x & 0xFFFF0000u);
    r2 = __uint_as_float((rw.y & 0xFFFFu) << 16); r3 = __uint_as_float(rw.y & 0xFFFF0000u);
  }
  r0 = fmaxf(r0, 0.f); r1 = fmaxf(r1, 0.f); r2 = fmaxf(r2, 0.f); r3 = fmaxf(r3, 0.f);
  long o = (long)b * NT + n;
  scores[o] = smax;
  *(float4*)(boxesw + o * 4) =
      make_float4(cx - r0 * stride, cy - r1 * stride, cx + r2 * stride, cy + r3 * stride);
  cidw[o] = (float)ci;
}

// ---------- wave64 inclusive scan ----------
__device__ __forceinline__ unsigned wscan(unsigned v, int lane) {
  for (int off = 1; off < 64; off <<= 1) {
    unsigned u = __shfl_up(v, off);
    if (lane >= off) v += u;
  }
  return v;
}

// ---------- K2: exact top-1000 (2-level histogram + hybrid bitonic) ----------
__global__ __launch_bounds__(1024)
void k_select(const float* scores, const float* boxesw, const float* cidw,
              float* topScore, float* topBox, float* topShift, float* topArea,
              unsigned long long* actInit) {
  const int b    = blockIdx.x;
  const int tid  = threadIdx.x;
  const int wid  = tid >> 6;
  const int lane = tid & 63;
  const float* sb = scores + (long)b * NT;

  __shared__ unsigned hist[8192];                       // 32 KB; aliased below
  unsigned long long* selKeys = (unsigned long long*)hist;  // [1024], alias (phase 2)
  __shared__ unsigned wsum[16];
  __shared__ unsigned sTop, sBefore, sSub, selCnt;
  __shared__ float redf[16];
  __shared__ float sMaxC;

  unsigned inv[21];
#pragma unroll
  for (int k = 0; k < 21; ++k)
    inv[k] = ~__float_as_uint(sb[tid + k * 1024]);

  // --- level 1: histogram of inv>>17 (15 bits, top 2 always 11 -> 8192 bins) ---
  for (int i = tid; i < 8192; i += 1024) hist[i] = 0u;
  __syncthreads();
#pragma unroll
  for (int k = 0; k < 21; ++k)
    atomicAdd(&hist[(inv[k] >> 17) - 0x6000u], 1u);
  __syncthreads();
  {
    unsigned hloc[8], s0 = 0;
#pragma unroll
    for (int j = 0; j < 8; ++j) { hloc[j] = hist[8 * tid + j]; s0 += hloc[j]; }
    unsigned sc = wscan(s0, lane);
    if (lane == 63) wsum[wid] = sc;
    __syncthreads();
    unsigned basev = 0;
    for (int w = 0; w < wid; ++w) basev += wsum[w];
    unsigned cumBefore = basev + sc - s0;
    if (cumBefore < TOPK && cumBefore + s0 >= TOPK) {
      unsigned c = cumBefore;
#pragma unroll
      for (int j = 0; j < 8; ++j) {
        if (c + hloc[j] >= TOPK) { sTop = (8 * tid + j) + 0x6000u; sBefore = c; break; }
        c += hloc[j];
      }
    }
  }
  __syncthreads();
  const unsigned topBits = sTop;
  const unsigned r = TOPK - sBefore;        // rank to reach inside boundary bin

  // --- level 2: histogram of bits 16..4 within boundary bin ---
  for (int i = tid; i < 8192; i += 1024) hist[i] = 0u;
  __syncthreads();
#pragma unroll
  for (int k = 0; k < 21; ++k)
    if ((inv[k] >> 17) == topBits) atomicAdd(&hist[(inv[k] >> 4) & 0x1FFFu], 1u);
  __syncthreads();
  {
    unsigned hloc[8], s0 = 0;
#pragma unroll
    for (int j = 0; j < 8; ++j) { hloc[j] = hist[8 * tid + j]; s0 += hloc[j]; }
    unsigned sc = wscan(s0, lane);
    if (lane == 63) wsum[wid] = sc;
    __syncthreads();
    unsigned basev = 0;
    for (int w = 0; w < wid; ++w) basev += wsum[w];
    unsigned cumBefore = basev + sc - s0;
    if (cumBefore < r && cumBefore + s0 >= r) {
      unsigned c = cumBefore;
#pragma unroll
      for (int j = 0; j < 8; ++j) {
        if (c + hloc[j] >= r) { sSub = 8 * tid + j; break; }
        c += hloc[j];
      }
    }
  }
  __syncthreads();
  // all inv strictly below cutEnd are selected (<= 999 + ties-in-16-ulp-subbin)
  const unsigned long long cutEnd =
      ((unsigned long long)topBits << 17) | ((unsigned long long)(sSub + 1u) << 4);
  if (tid == 0) selCnt = 0u;
  __syncthreads();   // hist reads done; selKeys alias now safe to write

#pragma unroll
  for (int k = 0; k < 21; ++k)
    if ((unsigned long long)inv[k] < cutEnd) {
      unsigned p = atomicAdd(&selCnt, 1u);
      if (p < 1024u) selKeys[p] = ((unsigned long long)inv[k] << 32) | (unsigned)(tid + k * 1024);
    }
  __syncthreads();
  unsigned total = selCnt < 1024u ? selCnt : 1024u;
  unsigned long long key =
      ((unsigned)tid < total) ? selKeys[tid] : 0xFFFFFFFFFFFFFFFFull;
  __syncthreads();

  // --- hybrid bitonic sort ascending: (inv asc, idx asc) == (score desc, idx asc) ---
  for (unsigned k = 2; k <= 1024; k <<= 1) {
    for (unsigned j = k >> 1; j > 0; j >>= 1) {
      unsigned long long other;
      if (j >= 64) {
        selKeys[tid] = key; __syncthreads();
        other = selKeys[tid ^ j]; __syncthreads();
      } else {
        other = __shfl(key, (int)(lane ^ j));      // partner within wave
      }
      bool up = ((tid & k) == 0);
      bool takeMin = (((tid & j) == 0) == up);
      key = takeMin ? (key < other ? key : other) : (key > other ? key : other);
    }
  }

  // --- epilogue: gather boxes, max_coord, shift, write top arrays ---
  float sc = __uint_as_float(~(unsigned)(key >> 32));
  float4 bv = make_float4(0.f, 0.f, 0.f, 0.f);
  float cid = 0.f;
  if (tid < TOPK) {
    long o = (long)b * NT + (unsigned)key;
    bv = *(const float4*)(boxesw + o * 4);
    cid = cidw[o];
  } else sc = 0.f;

  float loc = (tid < TOPK)
      ? ((sc > 0.3f) ? fmaxf(fmaxf(bv.x, bv.y), fmaxf(bv.z, bv.w)) : 0.0f)
      : -INFINITY;
  for (int o = 32; o > 0; o >>= 1) loc = fmaxf(loc, __shfl_down(loc, o));
  if (lane == 0) redf[wid] = loc;
  __syncthreads();
  if (tid == 0) {
    float m = redf[0];
    for (int w = 1; w < 16; ++w) m = fmaxf(m, redf[w]);
    sMaxC = m;
  }
  __syncthreads();

  float offm = sMaxC + 1.0f;
  long tb = (long)b * 1024 + tid;
  if (tid < TOPK) {
    float o4 = cid * offm;
    float s0 = bv.x + o4, s1 = bv.y + o4, s2 = bv.z + o4, s3 = bv.w + o4;
    *(float4*)(topShift + tb * 4) = make_float4(s0, s1, s2, s3);
    topArea[tb]  = (s2 - s0) * (s3 - s1);
    *(float4*)(topBox + tb * 4) = bv;
    topScore[tb] = sc;
  } else {
    *(float4*)(topShift + tb * 4) = make_float4(0.f, 0.f, 0.f, 0.f);
    topArea[tb]  = 0.f;
    *(float4*)(topBox + tb * 4) = make_float4(0.f, 0.f, 0.f, 0.f);
    topScore[tb] = 0.f;
  }
  unsigned long long vb = __ballot((tid < TOPK) && (sc > 0.3f));
  if (lane == 0) actInit[b * 16 + wid] = vb;
}

// ---------- K3: suppression bit-matrix (upper triangle only) ----------
// When row i is picked, every still-active j satisfies j > i (greedy + IoU
// symmetry), so words entirely below the diagonal are never consulted.
__global__ __launch_bounds__(1024)
void k_iou(const float* topShift, const float* topArea, unsigned* matrix) {
  const int wh  = blockIdx.x;
  const int b   = blockIdx.y;
  const int tid = threadIdx.x;
  const int jbase = (wh >> 1) * 64 + (wh & 1) * 32;
  __shared__ float jx0[32], jy0[32], jx1[32], jy1[32], ja[32];
  if (tid < 32) {
    long tj = (long)b * 1024 + jbase + tid;
    float4 s = *(const float4*)(topShift + tj * 4);
    jx0[tid] = s.x; jy0[tid] = s.y; jx1[tid] = s.z; jy1[tid] = s.w;
    ja[tid] = topArea[tj];
  }
  __syncthreads();
  if (tid > jbase + 31) return;                 // whole word below diagonal: unused
  long ti = (long)b * 1024 + tid;
  float4 si = *(const float4*)(topShift + ti * 4);
  float ai  = topArea[ti];
  unsigned word = 0u;
  for (int k = 0; k < 32; ++k) {
    float xx1 = fmaxf(si.x, jx0[k]);
    float yy1 = fmaxf(si.y, jy0[k]);
    float xx2 = fminf(si.z, jx1[k]);
    float yy2 = fminf(si.w, jy1[k]);
    float inter = fmaxf(xx2 - xx1, 0.f) * fmaxf(yy2 - yy1, 0.f);
    float iou = inter / (ai + ja[k] - inter);   // exact div: matches ref rounding
    if (!(iou <= 0.5f)) word |= (1u << k);      // NaN suppresses, like the ref
  }
  matrix[ti * 32 + wh] = word;
}

// ---------- K4: greedy scan over bit-matrix + det write ----------
__global__ __launch_bounds__(256)
void k_scan(const unsigned long long* matrix, const unsigned long long* actInit,
            const float* topBox, const float* topScore, void* out, const void* locs0) {
  const int bf   = detect_bf(locs0);
  const int b    = blockIdx.x;
  const int tid  = threadIdx.x;
  const int wid  = tid >> 6;
  const int lane = tid & 63;
  const unsigned long long* M = matrix + (long)b * 1024 * 16;

  __shared__ unsigned long long rows[2][64][16];   // double-buffered 64-row chunks
  __shared__ unsigned long long keepSh[16];

  unsigned long long act = 0ull, keep = 0ull;
  if (wid == 0 && lane < 16) act = actInit[b * 16 + lane];

  for (int t = tid; t < 1024; t += 256)
    rows[0][t >> 4][t & 15] = M[t];
  __syncthreads();

  int kept = 0;
  for (int c = 0; c < 16; ++c) {
    if (wid > 0) {
      if (c < 15) {
        for (int t = tid - 64; t < 1024; t += 192)
          rows[(c + 1) & 1][t >> 4][t & 15] = M[(long)(c + 1) * 1024 + t];
      }
    } else {
      unsigned long long cur = __shfl(act, c);
      while (cur && kept < 100) {
        int k = __ffsll((unsigned long long)cur) - 1;
        ++kept;
        if (lane == c) keep |= (1ull << k);
        unsigned long long rrow = (lane < 16) ? rows[c & 1][k][lane] : 0ull;
        act &= ~rrow;                            // self-bit clears the picked box
        cur = __shfl(act, c);
      }
    }
    __syncthreads();
  }
  if (wid == 0 && lane < 16) keepSh[lane] = keep;
  __syncthreads();

  for (int r = tid; r < TOPK; r += 256) {
    bool kp = (keepSh[r >> 6] >> (r & 63)) & 1ull;
    long tb = (long)b * 1024 + r;
    float4 bx = *(const float4*)(topBox + tb * 4);
    float sc  = topScore[tb];
    long o = ((long)b * TOPK + r) * 5;
    stout(out, o + 0, kp ? bx.x : 0.f, bf);
    stout(out, o + 1, kp ? bx.y : 0.f, bf);
    stout(out, o + 2, kp ? bx.z : 0.f, bf);
    stout(out, o + 3, kp ? bx.w : 0.f, bf);
    stout(out, o + 4, kp ? sc   : 0.f, bf);
  }
}

extern "C" void kernel_launch(void* const* d_in, const int* in_sizes, int n_in,
                              void* d_out, int out_size, void* d_ws, size_t ws_size,
                              hipStream_t stream) {
  const void* locs0 = d_in[0];
  const void* locs1 = d_in[1];
  const void* locs2 = d_in[2];
  const void* gt    = d_in[3];

  int ic[3], ir[3], it[3];
  if (n_in >= 13 && in_sizes[5] == 16 * 4096 * 20) {
    ic[0]=4; ic[1]=5; ic[2]=6;  ir[0]=7; ir[1]=8; ir[2]=9;  it[0]=10; it[1]=11; it[2]=12;
  } else {
    ic[0]=4; ic[1]=7; ic[2]=10; ir[0]=5; ir[1]=8; ir[2]=11; it[0]=6;  it[1]=9;  it[2]=12;
  }
  const void* cls0 = d_in[ic[0]]; const void* cls1 = d_in[ic[1]]; const void* cls2 = d_in[ic[2]];
  const void* reg0 = d_in[ir[0]]; const void* reg1 = d_in[ir[1]]; const void* reg2 = d_in[ir[2]];
  const void* ctr0 = d_in[it[0]]; const void* ctr1 = d_in[it[1]]; const void* ctr2 = d_in[it[2]];

  float* ws       = (float*)d_ws;
  float* scores   = ws + WS_SCORES;
  float* boxesw   = ws + WS_BOXESW;
  float* cidw     = ws + WS_CIDW;
  float* topScore = ws + WS_TOPSC;
  float* topBox   = ws + WS_TOPBOX;
  float* topShift = ws + WS_TOPSHIFT;
  float* topArea  = ws + WS_TOPAREA;
  unsigned long long* actInit = (unsigned long long*)(ws + WS_ACT);
  unsigned*           matrix32 = (unsigned*)(ws + WS_MATRIX);
  unsigned long long* matrix64 = (unsigned long long*)(ws + WS_MATRIX);

  k_main<<<dim3(NT / 256, NB), 256, 0, stream>>>(locs0, locs1, locs2, gt,
                                                 cls0, cls1, cls2,
                                                 reg0, reg1, reg2,
                                                 ctr0, ctr1, ctr2,
                                                 d_out, scores, boxesw, cidw);
  k_select<<<NB, 1024, 0, stream>>>(scores, boxesw, cidw,
                                    topScore, topBox, topShift, topArea, actInit);
  k_iou<<<dim3(32, NB), 1024, 0, stream>>>(topShift, topArea, matrix32);
  k_scan<<<NB, 256, 0, stream>>>(matrix64, actInit, topBox, topScore, d_out, locs0);
}